// Round 6
// baseline (93.139 us; speedup 1.0000x reference)
//
#include <hip/hip_runtime.h>
#include <stdint.h>

// ContrastiveLoss (SimCLR NT-Xent), B=4096, D=128, T=0.5
// loss = (1/2B) * sum_k log(denom_k)  -  (1/(B*T)) * sum_i dot(z_i, z_j_i)
//
// Round 7: persistent simexp. Round-5 analysis: each of 2080 blocks paid an
// un-overlapped stage+drain (~2k cyc) before ~1.5k cyc of compute -> simexp
// ~32us despite ~12us issue work. Now G=512 persistent blocks (2/CU), each
// ~4 tiles, with the T3-minimum 2-phase pipeline: STAGE(t+1 B-strip) into
// the other LDS buffer + prefetch A(t+1) regs BEFORE compute(t); the single
// per-tile __syncthreads (implicit vmcnt(0)) then drains loads that have had
// the whole compute phase to land. Col-sum export double-buffered, one tile
// late, overlapped with next tile's compute. Row-sums: direct float4 stores
// (no LDS, no extra barrier). Everything else (fragment layout, stage
// address math, diag mask, part[] single-writer mapping) identical to the
// verified round-5 kernel.

#define TEMP 0.5f
// exp(x/T) = exp2(x * log2(e)/T); T=0.5 -> scale = 2*log2(e)
#define EXP2_SCALE 2.885390081777927f

typedef __bf16 bf16_t;
typedef bf16_t bf16x8 __attribute__((ext_vector_type(8)));
typedef float floatx4 __attribute__((ext_vector_type(4)));

typedef __attribute__((address_space(3))) uint32_t lds_u32;
typedef const __attribute__((address_space(1))) uint32_t glb_u32;

__device__ __forceinline__ unsigned short f32_to_bf16(float f) {
    union { float f; uint32_t u; } v; v.f = f;
    uint32_t u = v.u;
    uint32_t r = (u + 0x7FFFu + ((u >> 16) & 1u)) >> 16;  // RNE
    return (unsigned short)r;
}

__device__ __forceinline__ bf16x8 as_bf16x8(uint4 v) {
    union { uint4 u; bf16x8 b; } c; c.u = v; return c.b;
}

// Raw hardware exp2/log2; args bounded away from denormal/overflow range.
__device__ __forceinline__ float exp2_raw(float x) {
#if __has_builtin(__builtin_amdgcn_exp2f)
    return __builtin_amdgcn_exp2f(x);
#else
    float r; asm("v_exp_f32 %0, %1" : "=v"(r) : "v"(x)); return r;
#endif
}
__device__ __forceinline__ float log2_raw(float x) {
#if __has_builtin(__builtin_amdgcn_logf)
    return __builtin_amdgcn_logf(x);
#else
    float r; asm("v_log_f32 %0, %1" : "=v"(r) : "v"(x)); return r;
#endif
}

// ---------------------------------------------------------------------------
// Kernel 1: per-row L2 normalize, bf16 reps[2B][128]; pos[i] = dot(z_i,z_j).
// Zeroes out[0] (no memset dispatch; part[] needs no zeroing at all).
// ---------------------------------------------------------------------------
__global__ __launch_bounds__(256) void norm_pos_kernel(
        const float* __restrict__ p1, const float* __restrict__ p2,
        unsigned short* __restrict__ reps, float* __restrict__ pos,
        float* __restrict__ out, int B) {
    if (blockIdx.x == 0 && threadIdx.x == 0) out[0] = 0.f;

    const int slot = threadIdx.x >> 5;  // 8 row-slots per block
    const int h    = threadIdx.x & 31;  // 32 lanes x float4 = one 128-f row
    const int i = blockIdx.x * 8 + slot;
    if (i >= B) return;

    float4 a = ((const float4*)(p1 + (size_t)i * 128))[h];
    float4 b = ((const float4*)(p2 + (size_t)i * 128))[h];
    float ss1 = a.x*a.x + a.y*a.y + a.z*a.z + a.w*a.w;
    float ss2 = b.x*b.x + b.y*b.y + b.z*b.z + b.w*b.w;
    float d   = a.x*b.x + a.y*b.y + a.z*b.z + a.w*b.w;
    #pragma unroll
    for (int off = 16; off > 0; off >>= 1) {   // stays within each 32-half
        ss1 += __shfl_xor(ss1, off);
        ss2 += __shfl_xor(ss2, off);
        d   += __shfl_xor(d,   off);
    }
    float rn1 = rsqrtf(fmaxf(ss1, 1e-24f));
    float rn2 = rsqrtf(fmaxf(ss2, 1e-24f));

    ((ushort4*)reps)[(size_t)i * 32 + h] = make_ushort4(
        f32_to_bf16(a.x*rn1), f32_to_bf16(a.y*rn1),
        f32_to_bf16(a.z*rn1), f32_to_bf16(a.w*rn1));
    ((ushort4*)reps)[(size_t)(B + i) * 32 + h] = make_ushort4(
        f32_to_bf16(b.x*rn2), f32_to_bf16(b.y*rn2),
        f32_to_bf16(b.z*rn2), f32_to_bf16(b.w*rn2));

    if (h == 0) pos[i] = d * rn1 * rn2;
}

// ---------------------------------------------------------------------------
// Kernel 2: persistent symmetric sim+exp, 2-phase pipelined, atomic-free.
// G=512 blocks x 4 waves; block b owns tiles b, b+G, b+2G, ... of the 2080
// upper-triangle 128x128 tiles. Per tile: STAGE(next B strip) + prefetch
// A(next) regs, export prev tile's col sums (overlapped), compute current
// tile from the ready LDS buffer, direct-store row sums, one barrier.
// ---------------------------------------------------------------------------
__global__ __launch_bounds__(256) void simexp_kernel(
        const unsigned short* __restrict__ reps,
        float* __restrict__ part, int nt, int N2, int nb, int G) {
    const int tid  = threadIdx.x;
    const int wave = tid >> 6;
    const int lane = tid & 63;
    const int quad = lane >> 4;
    const int l16  = lane & 15;

    __shared__ __align__(16) unsigned short bbuf[2][8][2048];  // 2 x 32 KB
    __shared__ float lds_cs[2][4][128];                        // dbuf col sums

    const uint4* g4 = (const uint4*)reps;  // 16 uint4 per 256-B row

    // stage one 128-col B strip (32 KB) into bbuf[c], per-lane fragment
    // order: panel ct at ct*4096 + tid*16 bytes (wave-uniform base + lane*16
    // = legal global_load_lds dest); per-lane global src gives frag order.
    auto stage = [&](int c, int colBase) {
        #pragma unroll
        for (int ct = 0; ct < 8; ++ct) {
            const unsigned short* src = reps
                + (size_t)(colBase + ct * 16 + l16) * 128 + wave * 32 + quad * 8;
            __builtin_amdgcn_global_load_lds(
                (glb_u32*)src, (lds_u32*)&bbuf[c][ct][tid * 8], 16, 0, 0);
        }
    };

    int t = (int)blockIdx.x;
    if (t >= nb) return;
    int rem = t, by = 0;
    while (rem >= nt - by) { rem -= nt - by; ++by; }
    int bx = by + rem;

    // A-fragment register sets: current and prefetch (2 row-tiles x 4 ks)
    bf16x8 aC[2][4], aN[2][4];
    #pragma unroll
    for (int tt = 0; tt < 2; ++tt)
        #pragma unroll
        for (int ks = 0; ks < 4; ++ks)
            aC[tt][ks] = as_bf16x8(
                g4[(size_t)(by * 128 + wave * 32 + tt * 16 + l16) * 16 + ks * 4 + quad]);
    stage(0, bx * 128);

    int cur = 0;
    int prev_by = 0, prev_bx = 0;
    bool prev_off = false;

    __syncthreads();  // prologue drain: bbuf[0] + aC resident (once/block)

    while (true) {
        const int nxt_t = t + G;
        const bool hasNext = nxt_t < nb;
        int nby = 0, nbx = 0;
        if (hasNext) {
            int r2 = nxt_t;
            while (r2 >= nt - nby) { r2 -= nt - nby; ++nby; }
            nbx = nby + r2;
            stage(cur ^ 1, nbx * 128);          // flies under compute below
            #pragma unroll
            for (int tt = 0; tt < 2; ++tt)
                #pragma unroll
                for (int ks = 0; ks < 4; ++ks)
                    aN[tt][ks] = as_bf16x8(
                        g4[(size_t)(nby * 128 + wave * 32 + tt * 16 + l16) * 16 + ks * 4 + quad]);
        }

        // export PREVIOUS tile's col sums (published by last barrier),
        // overlapped with this tile's compute on the other waves
        if (prev_off && tid < 128)
            part[(size_t)prev_by * N2 + prev_bx * 128 + tid] =
                lds_cs[cur ^ 1][0][tid] + lds_cs[cur ^ 1][1][tid]
              + lds_cs[cur ^ 1][2][tid] + lds_cs[cur ^ 1][3][tid];

        const bool diag = (bx == by);
        const int colBase = bx * 128;
        const int rowWave = by * 128 + wave * 32;

        float rs[2][4];
        #pragma unroll
        for (int tt = 0; tt < 2; ++tt)
            #pragma unroll
            for (int r = 0; r < 4; ++r) rs[tt][r] = 0.f;

        #pragma unroll
        for (int ct = 0; ct < 8; ++ct) {
            bf16x8 b[4];
            #pragma unroll
            for (int ks = 0; ks < 4; ++ks)
                b[ks] = *(const bf16x8*)&bbuf[cur][ct][ks * 512 + lane * 8];

            floatx4 acc[2];
            acc[0] = (floatx4){0.f, 0.f, 0.f, 0.f};
            acc[1] = (floatx4){0.f, 0.f, 0.f, 0.f};
            #pragma unroll
            for (int ks = 0; ks < 4; ++ks) {
                acc[0] = __builtin_amdgcn_mfma_f32_16x16x32_bf16(aC[0][ks], b[ks], acc[0], 0, 0, 0);
                acc[1] = __builtin_amdgcn_mfma_f32_16x16x32_bf16(aC[1][ks], b[ks], acc[1], 0, 0, 0);
            }

            if (!diag) {
                float cs = 0.f;
                #pragma unroll
                for (int tt = 0; tt < 2; ++tt)
                    #pragma unroll
                    for (int r = 0; r < 4; ++r) {
                        float e = exp2_raw(acc[tt][r] * EXP2_SCALE);
                        rs[tt][r] += e;
                        cs += e;
                    }
                cs += __shfl_xor(cs, 16);   // reduce across the 4 quads
                cs += __shfl_xor(cs, 32);
                if (lane < 16) lds_cs[cur][wave][ct * 16 + lane] = cs;
            } else {
                const int c = colBase + ct * 16 + l16;
                #pragma unroll
                for (int tt = 0; tt < 2; ++tt) {
                    const int rb = rowWave + tt * 16 + quad * 4;
                    #pragma unroll
                    for (int r = 0; r < 4; ++r) {
                        float e = (rb + r == c) ? 0.f
                                 : exp2_raw(acc[tt][r] * EXP2_SCALE);
                        rs[tt][r] += e;
                    }
                }
            }
        }

        // row-side: reduce across the 16 columns of each quad, then direct
        // float4 stores (unique writer per part entry; no LDS, no barrier)
        #pragma unroll
        for (int off = 1; off < 16; off <<= 1)
            #pragma unroll
            for (int tt = 0; tt < 2; ++tt)
                #pragma unroll
                for (int r = 0; r < 4; ++r)
                    rs[tt][r] += __shfl_xor(rs[tt][r], off);

        if (l16 == 0) {
            #pragma unroll
            for (int tt = 0; tt < 2; ++tt) {
                float4 v = make_float4(rs[tt][0], rs[tt][1], rs[tt][2], rs[tt][3]);
                *(float4*)&part[(size_t)bx * N2 + by * 128
                                + wave * 32 + tt * 16 + quad * 4] = v;
            }
        }

        if (hasNext) {
            #pragma unroll
            for (int tt = 0; tt < 2; ++tt)
                #pragma unroll
                for (int ks = 0; ks < 4; ++ks)
                    aC[tt][ks] = aN[tt][ks];
        }
        prev_by = by; prev_bx = bx; prev_off = !diag;

        __syncthreads();  // publish lds_cs[cur]; drain stage(next) (issued a
                          // whole compute-phase ago); protect bbuf[cur]
        cur ^= 1;
        if (!hasNext) break;
        t = nxt_t; by = nby; bx = nbx;
    }

    // epilogue: last tile's col sums (in lds_cs[cur^1] after final flip)
    if (prev_off && tid < 128)
        part[(size_t)prev_by * N2 + prev_bx * 128 + tid] =
            lds_cs[cur ^ 1][0][tid] + lds_cs[cur ^ 1][1][tid]
          + lds_cs[cur ^ 1][2][tid] + lds_cs[cur ^ 1][3][tid];
}

// ---------------------------------------------------------------------------
// Kernel 3: rowsum[r] = sum_k part[k][r] (coalesced, L2-resident), then
// out += mean(log(rowsum)) - sum(pos)/(B*T). One thread per row.
// ---------------------------------------------------------------------------
__global__ __launch_bounds__(256) void finalize_kernel(
        const float* __restrict__ part, const float* __restrict__ pos,
        float* __restrict__ out, int N2, int B, int nt) {
    const int r = blockIdx.x * 256 + threadIdx.x;   // grid covers N2 exactly
    float s = 0.f;
    #pragma unroll 8
    for (int k = 0; k < nt; ++k) s += part[(size_t)k * N2 + r];

    // log(x) = log2(x) * ln2
    float local = log2_raw(s) * (0.6931471805599453f / (float)N2);
    if (r < B) local -= pos[r] * (1.0f / ((float)B * TEMP));

    #pragma unroll
    for (int off = 32; off > 0; off >>= 1) local += __shfl_xor(local, off);

    __shared__ float wsum[4];
    const int wave = threadIdx.x >> 6, lane = threadIdx.x & 63;
    if (lane == 0) wsum[wave] = local;
    __syncthreads();
    if (threadIdx.x == 0)
        atomicAdd(out, wsum[0] + wsum[1] + wsum[2] + wsum[3]);
}

extern "C" void kernel_launch(void* const* d_in, const int* in_sizes, int n_in,
                              void* d_out, int out_size, void* d_ws, size_t ws_size,
                              hipStream_t stream) {
    const float* p1 = (const float*)d_in[0];
    const float* p2 = (const float*)d_in[1];
    float* out = (float*)d_out;

    const int B  = in_sizes[0] / 128;   // 4096
    const int N2 = 2 * B;               // 8192
    const int nt = N2 / 128;            // 64 row/col tiles
    const int nb = nt * (nt + 1) / 2;   // 2080 upper-triangle tiles

    // ws layout: [reps bf16: N2*256 B][part fp32: nt*N2*4 B][pos fp32: B*4 B]
    unsigned short* reps = (unsigned short*)d_ws;
    float* part = (float*)((char*)d_ws + (size_t)N2 * 256);
    float* pos  = part + (size_t)nt * N2;

    norm_pos_kernel<<<dim3((B + 7) / 8), dim3(256), 0, stream>>>(
        p1, p2, reps, pos, out, B);

    int G = 512;                        // 2 blocks/CU (LDS 69.6 KB each)
    if (G > nb) G = nb;
    simexp_kernel<<<dim3(G), dim3(256), 0, stream>>>(reps, part, nt, N2, nb, G);

    finalize_kernel<<<dim3(N2 / 256), dim3(256), 0, stream>>>(
        part, pos, out, N2, B, nt);
}